// Round 8
// baseline (307.297 us; speedup 1.0000x reference)
//
#include <hip/hip_runtime.h>

// SparseWeights: y = x @ (W_dense + scatter(sparse))^T + bias
// Round 8: LDS-traffic reduction. r2/r3/r6/r7 all ~1000-1060 TF because the
// shared per-CU LDS pipe (reads 192KB + writes 64KB per K-tile = ~2772cy)
// exceeds the MFMA wall (2483cy) at 128x64 wave tiles (read amp 3x).
// Fix: 4 waves x 128x128 wave tiles (read amp 2x): LDS 128KB reads + 64KB
// writes = ~2018cy < MFMA 2483cy -> MFMA-bound. 1 wave/SIMD (acc[8][8]=256
// regs + 128 operand regs ~ 410 < 512), 1 block/CU (128KiB LDS dbuf).
// One vmcnt(0)+barrier per tile; compiler emits counted lgkm waits for the
// ds_read->MFMA chain; SCHED0 pins cluster order.

typedef __attribute__((ext_vector_type(8))) __bf16 bf16x8;
typedef __attribute__((ext_vector_type(4))) float f32x4;
typedef __attribute__((ext_vector_type(8))) unsigned short u16x8;

#define BARRIER()   asm volatile("s_barrier" ::: "memory")
#define WAITVM0()   asm volatile("s_waitcnt vmcnt(0)" ::: "memory")
#define SCHED0()    __builtin_amdgcn_sched_barrier(0)

__device__ __forceinline__ unsigned short f2bf(float f) {
  unsigned int u = __builtin_bit_cast(unsigned int, f);
  u += 0x7FFFu + ((u >> 16) & 1u);   // round-to-nearest-even
  return (unsigned short)(u >> 16);
}

// ---- prepass 1/3: f32 -> bf16 bulk convert (vectorized x8) ----
__global__ __launch_bounds__(256) void cvt_f32_bf16(
    const float* __restrict__ s, unsigned short* __restrict__ d, long n8) {
  long i = (long)blockIdx.x * blockDim.x + threadIdx.x;
  const long stride = (long)gridDim.x * blockDim.x;
  for (; i < n8; i += stride) {
    const float4* sp = (const float4*)(s + i * 8);
    float4 a = sp[0];
    float4 b = sp[1];
    u16x8 o;
    o[0] = f2bf(a.x); o[1] = f2bf(a.y); o[2] = f2bf(a.z); o[3] = f2bf(a.w);
    o[4] = f2bf(b.x); o[5] = f2bf(b.y); o[6] = f2bf(b.z); o[7] = f2bf(b.w);
    *(u16x8*)(d + i * 8) = o;
  }
}

// ---- prepass 2/3: scatter sparse values into bf16 W ----
__global__ __launch_bounds__(256) void sparse_scatter(
    const float* __restrict__ dense, const float* __restrict__ vals,
    const int* __restrict__ rows, const int* __restrict__ cols,
    unsigned short* __restrict__ Wb, int nnz, int K) {
  int i = blockIdx.x * blockDim.x + threadIdx.x;
  if (i < nnz) {
    size_t off = (size_t)rows[i] * (size_t)K + (size_t)cols[i];
    Wb[off] = f2bf(dense[off] + vals[i]);
  }
}

// =====================================================================
// 256x256 GEMM, 256 threads = 4 waves (2Mx2N), wave tile 128x128 =
// acc[8][8] of 16x16x32 frags, BK=64 (kk=0,1). LDS: 2 x (A 32K + B 32K)
// = 128 KiB dbuf -> 1 block/CU -> 1 wave/SIMD. Rows = 128 B = 8 quads;
// LDS quad q of row r holds global quad q^(r&7) (pre-swizzled source,
// swizzled read; 0 conflicts measured r6/r7 with identical formulas).
// Tile t (buf = t&1): reads kk0 (16 ds_read_b128) | stage A(t+1) (8 gl)
// | reads kk1 (16) | stage B(t+1) (8 gl) | 64 MFMA kk0 | 64 MFMA kk1 |
// vmcnt(0) | barrier. Stages are ~2400cy old at the drain -> free.
// WAW: stage(t+1) targets buf^1 whose readers finished (lgkm-drained
// before their MFMAs) before the barrier ending tile t-1.
// =====================================================================
__global__ __launch_bounds__(256, 1) void gemm4w(
    const unsigned short* __restrict__ A,   // [Tm][K] bf16
    const unsigned short* __restrict__ B,   // [Mn][K] bf16
    const float* __restrict__ bias,
    float* __restrict__ C,
    int Tm, int Mn, int K) {
  extern __shared__ __align__(16) char smem[];   // 2 x 65536

  const int tid  = threadIdx.x;
  const int lane = tid & 63;
  const int wid  = tid >> 6;
  const int wm = (wid >> 1) * 128;
  const int wn = (wid & 1) * 128;

  // T1: XCD-aware bijective swizzle (nwg = 512, % 8 == 0)
  const int nwg = gridDim.x;
  int bid = blockIdx.x;
  if ((nwg & 7) == 0) bid = (bid & 7) * (nwg >> 3) + (bid >> 3);
  const int ntn = Mn >> 8;
  const int bm0 = (bid / ntn) << 8;
  const int bn0 = (bid % ntn) << 8;

  const int NT = K >> 6;             // K-tiles of 64

  // ---- staging: 256 threads, 16B each, 8 calls per 32KB half.
  // Call c: LDS byte c*4096 + tid*16 -> row c*32 + (tid>>3), quad tid&7.
  // Source: global row (c*32 + (tid>>3)), elem quad (tid&7)^((tid>>3)&7).
  const int sr  = tid >> 3;                          // 0..31
  const int gq8 = ((tid & 7) ^ (sr & 7)) * 8;        // pre-swizzled elem off
  const unsigned short* Asrc = A + (size_t)(bm0 + sr) * K + gq8;
  const unsigned short* Bsrc = B + (size_t)(bn0 + sr) * K + gq8;
  const size_t r32 = (size_t)32 * K;
  const int ldst = tid * 16;

#define STAGE8(SRC, LDSB, KOFF) do {                                             \
    _Pragma("unroll")                                                            \
    for (int c = 0; c < 8; ++c)                                                  \
      __builtin_amdgcn_global_load_lds(                                          \
        (const __attribute__((address_space(1))) void*)((SRC) + (size_t)c * r32 + (KOFF)), \
        (__attribute__((address_space(3))) void*)(smem + (LDSB) + c * 4096 + ldst), \
        16, 0, 0);                                                               \
  } while (0)

  // ---- read offsets: frag (row R, kk, cq) -> byte R*128 + ((kk*4+cq)^(R&7))*16
  const int fr = lane & 15, cq = lane >> 4;
  const int f7 = fr & 7;
  const int q0 = ((cq ^ f7) << 4);          // kk = 0
  const int q1 = (((4 + cq) ^ f7) << 4);    // kk = 1
  const int arow = (wm + fr) * 128;
  const int brow = (wn + fr) * 128;

  f32x4 acc[8][8] = {};
  bf16x8 a0[8], a1[8], b0[8], b1[8];

  // ---- prologue: stage tile 0 into buf 0 ----
  STAGE8(Asrc, 0, 0);
  STAGE8(Bsrc, 32768, 0);
  WAITVM0();
  BARRIER();

#pragma unroll 2
  for (int t = 0; t < NT; ++t) {
    const char* Ab = smem + (t & 1) * 65536;
    const char* Bb = Ab + 32768;
    const int nbase = ((t & 1) ^ 1) * 65536;
    const int kn = (t + 1) * 64;
    const bool st = (t + 1 < NT);

    // ---- reads kk0 (16 ds_read_b128) ----
#pragma unroll
    for (int m = 0; m < 8; ++m)
      a0[m] = *(const bf16x8*)(Ab + arow + m * 2048 + q0);
#pragma unroll
    for (int n = 0; n < 8; ++n)
      b0[n] = *(const bf16x8*)(Bb + brow + n * 2048 + q0);
    SCHED0();

    // ---- stage A(t+1) ----
    if (st) STAGE8(Asrc, nbase, kn);
    SCHED0();

    // ---- reads kk1 (16) ----
#pragma unroll
    for (int m = 0; m < 8; ++m)
      a1[m] = *(const bf16x8*)(Ab + arow + m * 2048 + q1);
#pragma unroll
    for (int n = 0; n < 8; ++n)
      b1[n] = *(const bf16x8*)(Bb + brow + n * 2048 + q1);
    SCHED0();

    // ---- stage B(t+1) ----
    if (st) STAGE8(Bsrc, nbase + 32768, kn);
    SCHED0();

    // ---- 64 MFMA kk0 (compiler inserts counted lgkm waits) ----
#pragma unroll
    for (int m = 0; m < 8; ++m)
#pragma unroll
      for (int n = 0; n < 8; ++n)
        acc[m][n] = __builtin_amdgcn_mfma_f32_16x16x32_bf16(a0[m], b0[n], acc[m][n], 0, 0, 0);
    SCHED0();

    // ---- 64 MFMA kk1 ----
#pragma unroll
    for (int m = 0; m < 8; ++m)
#pragma unroll
      for (int n = 0; n < 8; ++n)
        acc[m][n] = __builtin_amdgcn_mfma_f32_16x16x32_bf16(a1[m], b1[n], acc[m][n], 0, 0, 0);

    WAITVM0();     // stages issued ~1 full tile ago -> effectively free
    BARRIER();     // publish buf^1, release buf for overwrite
  }
#undef STAGE8

  // ---- epilogue: C/D layout col = lane&15, row = (lane>>4)*4 + q ----
  const int c4 = cq * 4;
#pragma unroll
  for (int n = 0; n < 8; ++n) {
    const int col = bn0 + wn + n * 16 + fr;
    const float bv = bias[col];
#pragma unroll
    for (int m = 0; m < 8; ++m) {
      const size_t rowb = (size_t)(bm0 + wm + m * 16 + c4);
#pragma unroll
      for (int q = 0; q < 4; ++q)
        C[(rowb + q) * (size_t)Mn + col] = acc[m][n][q] + bv;
    }
  }
}

extern "C" void kernel_launch(void* const* d_in, const int* in_sizes, int n_in,
                              void* d_out, int out_size, void* d_ws, size_t ws_size,
                              hipStream_t stream) {
  const float* x     = (const float*)d_in[0];
  const float* dw    = (const float*)d_in[1];
  const float* bias  = (const float*)d_in[2];
  const float* sv    = (const float*)d_in[3];
  const int*   rows  = (const int*)d_in[4];
  const int*   cols  = (const int*)d_in[5];
  float* out = (float*)d_out;

  const int  Mn = in_sizes[2];                       // 4096
  const long wElems = (long)in_sizes[1];             // M*K
  const int  K  = (int)(wElems / Mn);                // 4096
  const long xElems = (long)in_sizes[0];             // T*K
  const int  Tm = (int)(xElems / K);                 // 8192
  const int  nnz = in_sizes[3];

  unsigned short* Wb = (unsigned short*)d_ws;        // [M*K] bf16
  unsigned short* Xb = Wb + wElems;                  // [T*K] bf16

  cvt_f32_bf16<<<2048, 256, 0, stream>>>(dw, Wb, wElems / 8);
  sparse_scatter<<<(nnz + 255) / 256, 256, 0, stream>>>(dw, sv, rows, cols, Wb, nnz, K);
  cvt_f32_bf16<<<2048, 256, 0, stream>>>(x, Xb, xElems / 8);

  dim3 grid((Tm >> 8) * (Mn >> 8));                  // 32*16 = 512
  gemm4w<<<grid, 256, 131072, stream>>>(Xb, Wb, bias, out, Tm, Mn, K);
}

// Round 9
// 306.676 us; speedup vs baseline: 1.0020x; 1.0020x over previous
//
#include <hip/hip_runtime.h>

// SparseWeights: y = x @ (W_dense + scatter(sparse))^T + bias
// Round 9: r6's 8-phase structure + TRUE counted vmcnt (T4). One half-tile
// (2 global_load_lds) staged per phase with 3-6 phase leads; vmcnt(4) at
// phases 4 and 8 only — loads stay in flight ACROSS phase barriers (m218:
// counted-vs-drain0 within 8-phase = +38..73%). Ledger in comments below.

typedef __attribute__((ext_vector_type(8))) __bf16 bf16x8;
typedef __attribute__((ext_vector_type(4))) float f32x4;
typedef __attribute__((ext_vector_type(8))) unsigned short u16x8;

#define BARRIER()   asm volatile("s_barrier" ::: "memory")
#define WAITLGKM0() asm volatile("s_waitcnt lgkmcnt(0)" ::: "memory")
#define WAITVM(n)   asm volatile("s_waitcnt vmcnt(" #n ")" ::: "memory")
#define SCHED0()    __builtin_amdgcn_sched_barrier(0)

__device__ __forceinline__ unsigned short f2bf(float f) {
  unsigned int u = __builtin_bit_cast(unsigned int, f);
  u += 0x7FFFu + ((u >> 16) & 1u);   // round-to-nearest-even
  return (unsigned short)(u >> 16);
}

// ---- prepass 1/3: f32 -> bf16 bulk convert (vectorized x8) ----
__global__ __launch_bounds__(256) void cvt_f32_bf16(
    const float* __restrict__ s, unsigned short* __restrict__ d, long n8) {
  long i = (long)blockIdx.x * blockDim.x + threadIdx.x;
  const long stride = (long)gridDim.x * blockDim.x;
  for (; i < n8; i += stride) {
    const float4* sp = (const float4*)(s + i * 8);
    float4 a = sp[0];
    float4 b = sp[1];
    u16x8 o;
    o[0] = f2bf(a.x); o[1] = f2bf(a.y); o[2] = f2bf(a.z); o[3] = f2bf(a.w);
    o[4] = f2bf(b.x); o[5] = f2bf(b.y); o[6] = f2bf(b.z); o[7] = f2bf(b.w);
    *(u16x8*)(d + i * 8) = o;
  }
}

// ---- prepass 2/3: scatter sparse values into bf16 W ----
__global__ __launch_bounds__(256) void sparse_scatter(
    const float* __restrict__ dense, const float* __restrict__ vals,
    const int* __restrict__ rows, const int* __restrict__ cols,
    unsigned short* __restrict__ Wb, int nnz, int K) {
  int i = blockIdx.x * blockDim.x + threadIdx.x;
  if (i < nnz) {
    size_t off = (size_t)rows[i] * (size_t)K + (size_t)cols[i];
    Wb[off] = f2bf(dense[off] + vals[i]);
  }
}

// =====================================================================
// 256x256 GEMM, 512 threads = 8 waves (2Mx4N), wave tile 128x64 =
// acc[8][4] of 16x16x32 frags, BK=64 (kk=0,1). LDS 128 KiB: even tiles
// in buf0 {A@0(h0)/16384(h1), B@32768/49152}, odd in buf1 {A@65536/81920,
// B@98304/114688}. Rows 128 B = 8 quads; LDS quad q of row r holds global
// quad q^(r&7) (pre-swizzled src, swizzled read; 0 conflicts r6/r7/r8).
//
// Iteration j covers tiles e=2j (buf0) and o=2j+1 (buf1), 8 phases.
// Stage slots (1 half-tile = 2 gl_lds each):
//   P1: A0(o)   [buf1-A h0 freed @ j-1 P7; read @ P5 -> lead 4]
//   P2: A1(o)   [lead 3]
//   P3: B0(2j+2)[buf0-B freed @ P2; read @ j+1 P1 -> lead 6]
//   P4: B1(2j+2)[lead 5]; vmcnt(4); barrier
//   P5: A0(2j+2)[buf0-A freed @ P3; lead 4]
//   P6: A1(2j+2)[lead 3]
//   P7: B0(2j+3)[buf1-B freed @ P6; lead 6]
//   P8: B1(2j+3)[lead 5]; vmcnt(4); barrier
// vmcnt ledger (steady): enter iter with {B0,B1(o)} outstanding (4 loads);
// P4: 4+8=12 -> wait 4 drains {B(o),A(o)} (read P5) leaving {B(2j+2)};
// P8: 4+8=12 -> wait 4 drains {B(2j+2),A(2j+2)} (read j+1 P1) leaving
// {B(2j+3)} = next iter invariant. Tail: last iter P4 -> vmcnt(0).
// Phases P1-P3/P5-P7: {ds_reads; stage; barrier; lgkm0+SCHED0; prio1;
// 16 MFMA; prio0; barrier}. P4/P8: {stage; prio1; 16 MFMA; prio0;
// vmcnt; barrier}.
// =====================================================================
__global__ __launch_bounds__(512, 2) void gemm8p(
    const unsigned short* __restrict__ A,   // [Tm][K] bf16
    const unsigned short* __restrict__ B,   // [Mn][K] bf16
    const float* __restrict__ bias,
    float* __restrict__ C,
    int Tm, int Mn, int K) {
  extern __shared__ __align__(16) char smem[];   // 131072

  const int tid  = threadIdx.x;
  const int lane = tid & 63;
  const int wid  = tid >> 6;
  const int wm = (wid >> 2) * 128;
  const int wn = (wid & 3) * 64;

  // T1: XCD-aware bijective swizzle (nwg = 512, % 8 == 0)
  const int nwg = gridDim.x;
  int bid = blockIdx.x;
  if ((nwg & 7) == 0) bid = (bid & 7) * (nwg >> 3) + (bid >> 3);
  const int ntn = Mn >> 8;
  const int bm0 = (bid / ntn) << 8;
  const int bn0 = (bid % ntn) << 8;

  const int NT = K >> 6;             // K-tiles of 64 (even; K % 128 == 0)

  // ---- staging maps (identical to r6, correctness-verified) ----
  const int sr  = tid >> 3;                          // 0..63
  const int gq8 = ((tid & 7) ^ (sr & 7)) * 8;        // pre-swizzled elem off
  const unsigned short* Asrc = A + (size_t)(bm0 + sr) * K + gq8;
  const unsigned short* Bsrc = B + (size_t)(bn0 + sr) * K + gq8;
  const size_t r64 = (size_t)64 * K;
  const int ldst = tid * 16;

  // Stage ONE 16KB half-tile (128 rows) = 2 gl_lds: rows H*128..H*128+127.
#define STAGEH(SRC, H, LDSB, KOFF) do {                                          \
    __builtin_amdgcn_global_load_lds(                                            \
      (const __attribute__((address_space(1))) void*)((SRC) + (size_t)(H)*2*r64 + (KOFF)), \
      (__attribute__((address_space(3))) void*)(smem + (LDSB) + ldst), 16, 0, 0);\
    __builtin_amdgcn_global_load_lds(                                            \
      (const __attribute__((address_space(1))) void*)((SRC) + (size_t)(H)*2*r64 + r64 + (KOFF)), \
      (__attribute__((address_space(3))) void*)(smem + (LDSB) + 8192 + ldst), 16, 0, 0); \
  } while (0)

  // ---- read offsets: frag (row R, kk, cq) -> byte R*128 + ((kk*4+cq)^(R&7))*16
  const int fr = lane & 15, cq = lane >> 4;
  const int f7 = fr & 7;
  const int q0 = ((cq ^ f7) << 4);          // kk = 0
  const int q1 = (((4 + cq) ^ f7) << 4);    // kk = 1
  const int arow = (wm + fr) * 128;         // wave stays within one 16KB half
  const int brow = (wn + fr) * 128;

  f32x4 acc[8][4] = {};
  bf16x8 aq0[4], aq1[4], bA0[2], bA1[2], bB0[2], bB1[2];

  // ---- prologue: tile 0 (buf0) + B halves of tile 1 (buf1) ----
  STAGEH(Asrc, 0, 0, 0);
  STAGEH(Asrc, 1, 16384, 0);
  STAGEH(Bsrc, 0, 32768, 0);
  STAGEH(Bsrc, 1, 49152, 0);
  STAGEH(Bsrc, 0, 98304, 64);
  STAGEH(Bsrc, 1, 114688, 64);
  WAITVM(4);      // tile 0 landed; {B0,B1(1)} stay in flight
  BARRIER();

#define QUAD(MB, NB, AQ0, AQ1, BL0, BL1) do {                                    \
    __builtin_amdgcn_s_setprio(1);                                               \
    _Pragma("unroll")                                                            \
    for (int m = 0; m < 4; ++m)                                                  \
      _Pragma("unroll")                                                          \
      for (int n = 0; n < 2; ++n) {                                              \
        acc[m+(MB)][n+(NB)] = __builtin_amdgcn_mfma_f32_16x16x32_bf16(           \
            AQ0[m], BL0[n], acc[m+(MB)][n+(NB)], 0, 0, 0);                       \
        acc[m+(MB)][n+(NB)] = __builtin_amdgcn_mfma_f32_16x16x32_bf16(           \
            AQ1[m], BL1[n], acc[m+(MB)][n+(NB)], 0, 0, 0);                       \
      }                                                                          \
    __builtin_amdgcn_s_setprio(0);                                               \
  } while (0)

  for (int j = 0; j < (NT >> 1); ++j) {
    const int t2 = 2 * j + 2, t3 = 2 * j + 3;
    const int k1 = (2 * j + 1) << 6, k2 = t2 << 6, k3 = t3 << 6;
    const char* AbE = smem;            const char* BbE = smem + 32768;
    const char* AbO = smem + 65536;    const char* BbO = smem + 98304;

    // ---- P1: reads E{A m0-3, B n0-1}; stage A0(odd) ----
#pragma unroll
    for (int m = 0; m < 4; ++m) {
      aq0[m] = *(const bf16x8*)(AbE + arow + m * 2048 + q0);
      aq1[m] = *(const bf16x8*)(AbE + arow + m * 2048 + q1);
    }
#pragma unroll
    for (int n = 0; n < 2; ++n) {
      bA0[n] = *(const bf16x8*)(BbE + brow + n * 2048 + q0);
      bA1[n] = *(const bf16x8*)(BbE + brow + n * 2048 + q1);
    }
    STAGEH(Asrc, 0, 65536, k1);
    BARRIER(); WAITLGKM0(); SCHED0();
    QUAD(0, 0, aq0, aq1, bA0, bA1);
    BARRIER();

    // ---- P2: reads E{B n2-3}; stage A1(odd) ----
#pragma unroll
    for (int n = 0; n < 2; ++n) {
      bB0[n] = *(const bf16x8*)(BbE + brow + (n + 2) * 2048 + q0);
      bB1[n] = *(const bf16x8*)(BbE + brow + (n + 2) * 2048 + q1);
    }
    STAGEH(Asrc, 1, 81920, k1);
    BARRIER(); WAITLGKM0(); SCHED0();
    QUAD(0, 2, aq0, aq1, bB0, bB1);
    BARRIER();

    // ---- P3: reads E{A m4-7}; stage B0(t2) ----
#pragma unroll
    for (int m = 0; m < 4; ++m) {
      aq0[m] = *(const bf16x8*)(AbE + arow + (m + 4) * 2048 + q0);
      aq1[m] = *(const bf16x8*)(AbE + arow + (m + 4) * 2048 + q1);
    }
    if (t2 < NT) STAGEH(Bsrc, 0, 32768, k2);
    BARRIER(); WAITLGKM0(); SCHED0();
    QUAD(4, 0, aq0, aq1, bA0, bA1);
    BARRIER();

    // ---- P4: stage B1(t2); MFMA; counted vmcnt; publish odd tile ----
    if (t2 < NT) STAGEH(Bsrc, 1, 49152, k2);
    QUAD(4, 2, aq0, aq1, bB0, bB1);
    if (t2 < NT) { WAITVM(4); } else { WAITVM(0); }
    BARRIER();

    // ---- P5: reads O{A m0-3, B n0-1}; stage A0(t2) ----
#pragma unroll
    for (int m = 0; m < 4; ++m) {
      aq0[m] = *(const bf16x8*)(AbO + arow + m * 2048 + q0);
      aq1[m] = *(const bf16x8*)(AbO + arow + m * 2048 + q1);
    }
#pragma unroll
    for (int n = 0; n < 2; ++n) {
      bA0[n] = *(const bf16x8*)(BbO + brow + n * 2048 + q0);
      bA1[n] = *(const bf16x8*)(BbO + brow + n * 2048 + q1);
    }
    if (t2 < NT) STAGEH(Asrc, 0, 0, k2);
    BARRIER(); WAITLGKM0(); SCHED0();
    QUAD(0, 0, aq0, aq1, bA0, bA1);
    BARRIER();

    // ---- P6: reads O{B n2-3}; stage A1(t2) ----
#pragma unroll
    for (int n = 0; n < 2; ++n) {
      bB0[n] = *(const bf16x8*)(BbO + brow + (n + 2) * 2048 + q0);
      bB1[n] = *(const bf16x8*)(BbO + brow + (n + 2) * 2048 + q1);
    }
    if (t2 < NT) STAGEH(Asrc, 1, 16384, k2);
    BARRIER(); WAITLGKM0(); SCHED0();
    QUAD(0, 2, aq0, aq1, bB0, bB1);
    BARRIER();

    // ---- P7: reads O{A m4-7}; stage B0(t3) ----
#pragma unroll
    for (int m = 0; m < 4; ++m) {
      aq0[m] = *(const bf16x8*)(AbO + arow + (m + 4) * 2048 + q0);
      aq1[m] = *(const bf16x8*)(AbO + arow + (m + 4) * 2048 + q1);
    }
    if (t3 < NT) STAGEH(Bsrc, 0, 98304, k3);
    BARRIER(); WAITLGKM0(); SCHED0();
    QUAD(4, 0, aq0, aq1, bA0, bA1);
    BARRIER();

    // ---- P8: stage B1(t3); MFMA; counted vmcnt; publish even tile ----
    if (t3 < NT) STAGEH(Bsrc, 1, 114688, k3);
    QUAD(4, 2, aq0, aq1, bB0, bB1);
    if (t3 < NT) { WAITVM(4); } else if (t2 < NT) { WAITVM(0); }
    BARRIER();
  }
#undef QUAD
#undef STAGEH

  // ---- epilogue: C/D layout col = lane&15, row = (lane>>4)*4 + q ----
  const int c4 = cq * 4;
#pragma unroll
  for (int n = 0; n < 4; ++n) {
    const int col = bn0 + wn + n * 16 + fr;
    const float bv = bias[col];
#pragma unroll
    for (int m = 0; m < 8; ++m) {
      const size_t rowb = (size_t)(bm0 + wm + m * 16 + c4);
#pragma unroll
      for (int q = 0; q < 4; ++q)
        C[(rowb + q) * (size_t)Mn + col] = acc[m][n][q] + bv;
    }
  }
}

extern "C" void kernel_launch(void* const* d_in, const int* in_sizes, int n_in,
                              void* d_out, int out_size, void* d_ws, size_t ws_size,
                              hipStream_t stream) {
  const float* x     = (const float*)d_in[0];
  const float* dw    = (const float*)d_in[1];
  const float* bias  = (const float*)d_in[2];
  const float* sv    = (const float*)d_in[3];
  const int*   rows  = (const int*)d_in[4];
  const int*   cols  = (const int*)d_in[5];
  float* out = (float*)d_out;

  const int  Mn = in_sizes[2];                       // 4096
  const long wElems = (long)in_sizes[1];             // M*K
  const int  K  = (int)(wElems / Mn);                // 4096
  const long xElems = (long)in_sizes[0];             // T*K
  const int  Tm = (int)(xElems / K);                 // 8192
  const int  nnz = in_sizes[3];

  unsigned short* Wb = (unsigned short*)d_ws;        // [M*K] bf16
  unsigned short* Xb = Wb + wElems;                  // [T*K] bf16

  cvt_f32_bf16<<<2048, 256, 0, stream>>>(dw, Wb, wElems / 8);
  sparse_scatter<<<(nnz + 255) / 256, 256, 0, stream>>>(dw, sv, rows, cols, Wb, nnz, K);
  cvt_f32_bf16<<<2048, 256, 0, stream>>>(x, Xb, xElems / 8);

  dim3 grid((Tm >> 8) * (Mn >> 8));                  // 32*16 = 512
  gemm8p<<<grid, 512, 131072, stream>>>(Xb, Wb, bias, out, Tm, Mn, K);
}